// Round 1
// baseline (680.766 us; speedup 1.0000x reference)
//
#include <hip/hip_runtime.h>
#include <math.h>

// Codebook argmin: B=16, K=512, C=512, H=W=64.
// argmin_k ||x_p - c_k||^2 == argmax_k (cross[p,k] - 0.5*c_sq[k])  (x_sq drops out)
// Main kernel: fp32 register-tiled GEMM (32 pixels x 512 clusters per block)
// with fused argmax epilogue. Near-ties (gap < MARGIN) re-checked in fp64.

#define NK   512    // clusters
#define NC   512    // channels
#define NHW  4096   // H*W per batch
#define TPIX 32     // pixels per block
#define BK   16     // C chunk staged in LDS
#define MARGIN 0.05f

__global__ __launch_bounds__(64) void prep_kernel(const float* __restrict__ cc,
                                                  float* __restrict__ ccT,
                                                  float* __restrict__ shalf) {
    const int k = blockIdx.x;       // one block per cluster row
    const int lane = threadIdx.x;   // 64 threads = 1 wave
    const float* row = cc + (size_t)k * NC;
    float sum = 0.0f;
    for (int c = lane; c < NC; c += 64) {
        float v = row[c];
        sum = fmaf(v, v, sum);
        ccT[(size_t)c * NK + k] = v;   // transpose: ccT[c][k]
    }
    for (int off = 32; off > 0; off >>= 1)
        sum += __shfl_down(sum, off, 64);
    if (lane == 0) shalf[k] = 0.5f * sum;
}

__global__ __launch_bounds__(256) void codebook_kernel(
        const float* __restrict__ x,
        const float* __restrict__ cc,
        const float* __restrict__ ccT,
        const float* __restrict__ shalf,
        int* __restrict__ out) {
    __shared__ float xs[BK][TPIX];          // 2 KB
    __shared__ float cs[BK][NK];            // 32 KB
    __shared__ float red_v [TPIX][33];      // padded rows: no bank conflict in scan
    __shared__ float red_v2[TPIX][33];
    __shared__ int   red_i [TPIX][33];
    __shared__ float xcol[NC];
    __shared__ double dv[256];
    __shared__ int    di[256];
    __shared__ int    flagsh[TPIX];
    __shared__ int    bestk_sh[TPIX];

    const int tid = threadIdx.x;
    const int tx = tid & 31;    // cluster group: k = j4*128 + tx*4 + jj (b128, conflict-free)
    const int ty = tid >> 5;    // pixel group: pixels ty*4 .. ty*4+3

    const int gp0 = blockIdx.x * TPIX;      // 4096 % 32 == 0 -> block never crosses batch
    const int b   = gp0 >> 12;
    const int hw0 = gp0 & (NHW - 1);
    const float* xb = x + (size_t)b * NC * NHW + hw0;

    float acc[4][16];
    #pragma unroll
    for (int i = 0; i < 4; ++i)
        #pragma unroll
        for (int j = 0; j < 16; ++j) acc[i][j] = 0.0f;

    const float4* ccT4 = (const float4*)ccT;

    for (int c0 = 0; c0 < NC; c0 += BK) {
        __syncthreads();
        // stage x chunk: 16 rows x 32 pixels = 128 float4
        if (tid < 128) {
            int cr  = tid >> 3;
            int off = (tid & 7) << 2;
            float4 v = *(const float4*)(xb + (size_t)(c0 + cr) * NHW + off);
            *(float4*)&xs[cr][off] = v;
        }
        // stage ccT chunk: contiguous 32 KB in ws -> fully coalesced
        #pragma unroll
        for (int j = 0; j < 8; ++j) {
            int f4 = j * 256 + tid;
            ((float4*)cs)[f4] = ccT4[c0 * (NK / 4) + f4];
        }
        __syncthreads();
        #pragma unroll
        for (int c = 0; c < BK; ++c) {
            float4 av = *(const float4*)&xs[c][ty * 4];          // broadcast
            float4 b0 = *(const float4*)&cs[c][      tx * 4];    // lanes 16B apart
            float4 b1 = *(const float4*)&cs[c][128 + tx * 4];
            float4 b2 = *(const float4*)&cs[c][256 + tx * 4];
            float4 b3 = *(const float4*)&cs[c][384 + tx * 4];
            float bv[16] = {b0.x, b0.y, b0.z, b0.w, b1.x, b1.y, b1.z, b1.w,
                            b2.x, b2.y, b2.z, b2.w, b3.x, b3.y, b3.z, b3.w};
            float av_[4] = {av.x, av.y, av.z, av.w};
            #pragma unroll
            for (int j = 0; j < 16; ++j)
                #pragma unroll
                for (int i = 0; i < 4; ++i)
                    acc[i][j] = fmaf(av_[i], bv[j], acc[i][j]);
        }
    }

    // load 0.5*c_sq for my 16 clusters, per-thread top-2 argmax per pixel
    float sv[16];
    {
        const float4* s4 = (const float4*)shalf;
        float4 t0 = s4[tx], t1 = s4[32 + tx], t2 = s4[64 + tx], t3 = s4[96 + tx];
        sv[0]=t0.x; sv[1]=t0.y; sv[2]=t0.z; sv[3]=t0.w;
        sv[4]=t1.x; sv[5]=t1.y; sv[6]=t1.z; sv[7]=t1.w;
        sv[8]=t2.x; sv[9]=t2.y; sv[10]=t2.z; sv[11]=t2.w;
        sv[12]=t3.x; sv[13]=t3.y; sv[14]=t3.z; sv[15]=t3.w;
    }
    #pragma unroll
    for (int i = 0; i < 4; ++i) {
        float best = -INFINITY, sec = -INFINITY;
        int bk = 1 << 30;
        #pragma unroll
        for (int j = 0; j < 16; ++j) {
            int k = (j >> 2) * 128 + tx * 4 + (j & 3);
            float v = acc[i][j] - sv[j];
            if (v > best || (v == best && k < bk)) { sec = best; best = v; bk = k; }
            else if (v > sec) sec = v;
        }
        int pl = ty * 4 + i;
        red_v [pl][tx] = best;
        red_v2[pl][tx] = sec;
        red_i [pl][tx] = bk;
    }
    __syncthreads();

    if (tid < TPIX) {
        const int pix = tid;
        float best = -INFINITY, sec = -INFINITY;
        int bk = 1 << 30;
        for (int t = 0; t < 32; ++t) {
            float v  = red_v [pix][t];
            float v2 = red_v2[pix][t];
            int   kk = red_i [pix][t];
            if (v > best || (v == best && kk < bk)) {
                sec = fmaxf(sec, best);
                best = v; bk = kk;
            } else {
                sec = fmaxf(sec, v);
            }
            sec = fmaxf(sec, v2);
        }
        bestk_sh[pix] = bk;
        flagsh[pix] = (best - sec < MARGIN) ? 1 : 0;
    }
    __syncthreads();

    // fp64 full re-check for near-tie pixels (rare; ~0.6% of pixels)
    for (int pix = 0; pix < TPIX; ++pix) {
        if (!flagsh[pix]) continue;          // uniform branch (all lanes read same LDS)
        for (int c = tid; c < NC; c += 256)
            xcol[c] = xb[(size_t)c * NHW + pix];
        __syncthreads();
        double bd = 1e300;
        int bkk = 1 << 30;
        #pragma unroll
        for (int r = 0; r < 2; ++r) {
            int k = tid + r * 256;
            const float4* crow = (const float4*)(cc + (size_t)k * NC);
            const float4* xc4  = (const float4*)xcol;
            double d = 0.0;
            for (int c4 = 0; c4 < NC / 4; ++c4) {
                float4 cv = crow[c4];
                float4 xv = xc4[c4];
                double d0 = (double)xv.x - (double)cv.x;
                double d1 = (double)xv.y - (double)cv.y;
                double d2 = (double)xv.z - (double)cv.z;
                double d3 = (double)xv.w - (double)cv.w;
                d = fma(d0, d0, d);
                d = fma(d1, d1, d);
                d = fma(d2, d2, d);
                d = fma(d3, d3, d);
            }
            if (d < bd || (d == bd && k < bkk)) { bd = d; bkk = k; }
        }
        dv[tid] = bd; di[tid] = bkk;
        __syncthreads();
        for (int srd = 128; srd > 0; srd >>= 1) {
            if (tid < srd) {
                double ov = dv[tid + srd]; int oi = di[tid + srd];
                if (ov < dv[tid] || (ov == dv[tid] && oi < di[tid])) {
                    dv[tid] = ov; di[tid] = oi;
                }
            }
            __syncthreads();
        }
        if (tid == 0) bestk_sh[pix] = di[0];
        __syncthreads();
    }

    if (tid < TPIX) out[gp0 + tid] = bestk_sh[tid];
}

extern "C" void kernel_launch(void* const* d_in, const int* in_sizes, int n_in,
                              void* d_out, int out_size, void* d_ws, size_t ws_size,
                              hipStream_t stream) {
    const float* x  = (const float*)d_in[0];   // (16, 512, 64, 64) f32
    const float* cc = (const float*)d_in[1];   // (1, 512, 512, 1, 1) f32 -> [k][c]
    int* out = (int*)d_out;                    // (16, 1, 64, 64) int32

    float* shalf = (float*)d_ws;               // 512 floats: 0.5*c_sq
    float* ccT   = shalf + NK;                 // 512*512 floats: ccT[c][k]

    prep_kernel<<<NK, 64, 0, stream>>>(cc, ccT, shalf);
    codebook_kernel<<<(16 * NHW) / TPIX, 256, 0, stream>>>(x, cc, ccT, shalf, out);
}

// Round 2
// 355.610 us; speedup vs baseline: 1.9144x; 1.9144x over previous
//
#include <hip/hip_runtime.h>
#include <math.h>

// Codebook argmin via split-bf16 MFMA: B=16, K=512, C=512, H=W=64.
// cross = xh*ch + xh*cl + xl*ch  (3x v_mfma_f32_32x32x16_bf16), error ~1.5e-4.
// Block: 512 clusters (M) x 64 pixels (N); wave = 4 m-tiles x 2 n-tiles.
// Epilogue: per-lane in-register top-2 over 64 clusters (C/D col = pixel),
// 8-slot LDS combine; near-ties (gap < MARGIN) re-checked in fp64.

#define NK   512
#define NC   512
#define NHW  4096
#define MARGIN 0.02f

typedef unsigned short u16;
typedef __attribute__((ext_vector_type(8)))  short  short8;
typedef __attribute__((ext_vector_type(8)))  unsigned short ushort8;
typedef __attribute__((ext_vector_type(16))) float  f32x16;

__device__ __forceinline__ u16 f2bf(float f) {
    unsigned u = __builtin_bit_cast(unsigned, f);
    u += 0x7FFFu + ((u >> 16) & 1u);          // round-to-nearest-even bf16
    return (u16)(u >> 16);
}
__device__ __forceinline__ float bf2f(u16 h) {
    unsigned u = ((unsigned)h) << 16;
    return __builtin_bit_cast(float, u);
}

// Pack cluster centers into MFMA A-operand fragment order (hi & lo planes) and
// compute 0.5*c_sq. ws layout: wcc[chunk 32][unit 32][lane 64][8 bf16];
// unit u<16 -> hi of m-tile u, u>=16 -> lo of m-tile u-16.
__global__ __launch_bounds__(64) void prep_pack(const float* __restrict__ cc,
                                                u16* __restrict__ wcc,
                                                float* __restrict__ shalf) {
    const int k    = blockIdx.x;
    const int lane = threadIdx.x;      // 64 j-groups of 8 channels
    const int c0   = lane * 8;
    const float* row = cc + (size_t)k * NC + c0;
    ushort8 hi, lo;
    float sum = 0.f;
    #pragma unroll
    for (int i = 0; i < 8; ++i) {
        float v = row[i];
        sum = fmaf(v, v, sum);
        u16 h = f2bf(v);
        hi[i] = h;
        lo[i] = f2bf(v - bf2f(h));
    }
    const int ch = c0 >> 4;            // 16-channel chunk
    const int kh = (c0 >> 3) & 1;      // which 8-chan half of the chunk
    const int mt = k >> 5;             // m-tile
    const int ls = (k & 31) + 32 * kh; // lane slot in fragment
    *(ushort8*)(wcc + ((size_t)(ch * 32 + mt)      * 64 + ls) * 8) = hi;
    *(ushort8*)(wcc + ((size_t)(ch * 32 + 16 + mt) * 64 + ls) * 8) = lo;
    #pragma unroll
    for (int off = 32; off > 0; off >>= 1) sum += __shfl_down(sum, off, 64);
    if (lane == 0) shalf[k] = 0.5f * sum;
}

__global__ __launch_bounds__(256, 2) void codebook_mfma(
        const float* __restrict__ x,
        const float* __restrict__ cc,
        const u16* __restrict__ wcc,
        const float* __restrict__ shalf,
        int* __restrict__ out)
{
    __shared__ __align__(16) u16 cs[32 * 512];   // 32 units x 1KB = 32KB (epilogue overlay)
    __shared__ __align__(16) u16 xsm[4 * 512];   // [hl 2][nt 2][lane 64][8] = 4KB
    __shared__ float sh_s[NK];
    __shared__ int   flagsh[64];
    __shared__ int   bestk_sh[64];

    const int tid  = threadIdx.x;
    const int w    = tid >> 6;
    const int lane = tid & 63;

    const int gp0 = blockIdx.x * 64;             // 4096 % 64 == 0: no batch crossing
    const float* xb = x + (size_t)(gp0 >> 12) * (NC * NHW) + (gp0 & (NHW - 1));

    sh_s[tid]       = shalf[tid];
    sh_s[tid + 256] = shalf[tid + 256];

    f32x16 acc[4][2] = {};

    // x staging assignment: pixel p, chunk-half kh, j-quarter jq (4 channels)
    const int p  = tid & 63;
    const int xkh = w & 1;
    const int jq  = w >> 1;
    u16* xw_hi = &xsm[((0 * 2 + (p >> 5)) * 64 + ((p & 31) + 32 * xkh)) * 8 + jq * 4];
    u16* xw_lo = xw_hi + 2 * 512;
    const float* xp = xb + (size_t)(xkh * 8 + jq * 4) * NHW + p;

    for (int ch = 0; ch < 32; ++ch) {
        __syncthreads();
        // cluster frags: async global->LDS DMA, dest = unit base + lane*16
        #pragma unroll
        for (int i = 0; i < 8; ++i) {
            const int u = w * 8 + i;
            const u16* g = wcc + ((size_t)(ch * 32 + u) * 64 + lane) * 8;
            __builtin_amdgcn_global_load_lds(
                (const __attribute__((address_space(1))) void*)g,
                (__attribute__((address_space(3))) void*)&cs[u * 512],
                16, 0, 0);
        }
        // x: load 4 channels for my pixel, split hi/lo, write frag-ordered
        const float* xc = xp + (size_t)ch * 16 * NHW;
        float f0 = xc[0];
        float f1 = xc[NHW];
        float f2 = xc[2 * NHW];
        float f3 = xc[3 * NHW];
        u16 h0 = f2bf(f0), h1 = f2bf(f1), h2 = f2bf(f2), h3 = f2bf(f3);
        u16 l0 = f2bf(f0 - bf2f(h0)), l1 = f2bf(f1 - bf2f(h1));
        u16 l2 = f2bf(f2 - bf2f(h2)), l3 = f2bf(f3 - bf2f(h3));
        uint2 hv = make_uint2((unsigned)h0 | ((unsigned)h1 << 16),
                              (unsigned)h2 | ((unsigned)h3 << 16));
        uint2 lv = make_uint2((unsigned)l0 | ((unsigned)l1 << 16),
                              (unsigned)l2 | ((unsigned)l3 << 16));
        *(uint2*)xw_hi = hv;
        *(uint2*)xw_lo = lv;
        __syncthreads();

        short8 bh[2], bl[2];
        #pragma unroll
        for (int nt = 0; nt < 2; ++nt) {
            bh[nt] = *(const short8*)&xsm[((0 * 2 + nt) * 64 + lane) * 8];
            bl[nt] = *(const short8*)&xsm[((1 * 2 + nt) * 64 + lane) * 8];
        }
        #pragma unroll
        for (int mt = 0; mt < 4; ++mt) {
            const int gm = w * 4 + mt;
            short8 ah = *(const short8*)&cs[((size_t)gm * 64 + lane) * 8];
            short8 al = *(const short8*)&cs[((size_t)(16 + gm) * 64 + lane) * 8];
            #pragma unroll
            for (int nt = 0; nt < 2; ++nt) {
                acc[mt][nt] = __builtin_amdgcn_mfma_f32_32x32x16_bf16(ah, bh[nt], acc[mt][nt], 0, 0, 0);
                acc[mt][nt] = __builtin_amdgcn_mfma_f32_32x32x16_bf16(al, bh[nt], acc[mt][nt], 0, 0, 0);
                acc[mt][nt] = __builtin_amdgcn_mfma_f32_32x32x16_bf16(ah, bl[nt], acc[mt][nt], 0, 0, 0);
            }
        }
    }
    __syncthreads();

    // ---- epilogue (overlays cs) ----
    double* dvv    = (double*)cs;            // 2KB
    int*    dii    = (int*)(dvv + 256);      // 1KB
    float*  xcol   = (float*)(dii + 256);    // 2KB
    float*  cand_v = xcol + NC;              // 2KB
    float*  cand_s = cand_v + 512;           // 2KB
    int*    cand_k = (int*)(cand_s + 512);   // 2KB

    const int qb = lane >> 5;
    #pragma unroll
    for (int nt = 0; nt < 2; ++nt) {
        float best = -INFINITY, sec = -INFINITY;
        int bk = 0;
        #pragma unroll
        for (int mt = 0; mt < 4; ++mt) {
            const int kbase = w * 128 + mt * 32 + 4 * qb;
            #pragma unroll
            for (int reg = 0; reg < 16; ++reg) {
                const int k = kbase + (reg & 3) + 8 * (reg >> 2);  // ascending in k
                const float v = acc[mt][nt][reg] - sh_s[k];
                if (v > best) { sec = best; best = v; bk = k; }
                else if (v > sec) sec = v;
            }
        }
        const int pc   = nt * 32 + (lane & 31);
        const int slot = w * 2 + qb;
        cand_v[pc * 8 + slot] = best;
        cand_s[pc * 8 + slot] = sec;
        cand_k[pc * 8 + slot] = bk;
    }
    __syncthreads();

    if (tid < 64) {
        float best = -INFINITY, sec = -INFINITY;
        int bk = 1 << 30;
        #pragma unroll
        for (int s = 0; s < 8; ++s) {
            float v  = cand_v[tid * 8 + s];
            float v2 = cand_s[tid * 8 + s];
            int  kk  = cand_k[tid * 8 + s];
            if (v > best || (v == best && kk < bk)) {
                sec = fmaxf(sec, best);
                best = v; bk = kk;
            } else sec = fmaxf(sec, v);
            sec = fmaxf(sec, v2);
        }
        bestk_sh[tid] = bk;
        flagsh[tid] = (best - sec < MARGIN) ? 1 : 0;
    }
    __syncthreads();

    // fp64 full re-check for near-tie pixels (rare)
    for (int pix = 0; pix < 64; ++pix) {
        if (!flagsh[pix]) continue;              // uniform (LDS) branch
        for (int c = tid; c < NC; c += 256)
            xcol[c] = xb[(size_t)c * NHW + pix];
        __syncthreads();
        double bd = 1e300;
        int bkk = 1 << 30;
        #pragma unroll
        for (int r = 0; r < 2; ++r) {
            const int k = tid + r * 256;
            const float4* crow = (const float4*)(cc + (size_t)k * NC);
            const float4* xc4  = (const float4*)xcol;
            double d = 0.0;
            for (int c4 = 0; c4 < NC / 4; ++c4) {
                float4 cv = crow[c4], xv = xc4[c4];
                double d0 = (double)xv.x - (double)cv.x;
                double d1 = (double)xv.y - (double)cv.y;
                double d2 = (double)xv.z - (double)cv.z;
                double d3 = (double)xv.w - (double)cv.w;
                d = fma(d0, d0, d); d = fma(d1, d1, d);
                d = fma(d2, d2, d); d = fma(d3, d3, d);
            }
            if (d < bd || (d == bd && k < bkk)) { bd = d; bkk = k; }
        }
        dvv[tid] = bd; dii[tid] = bkk;
        __syncthreads();
        for (int srd = 128; srd > 0; srd >>= 1) {
            if (tid < srd) {
                double ov = dvv[tid + srd]; int oi = dii[tid + srd];
                if (ov < dvv[tid] || (ov == dvv[tid] && oi < dii[tid])) {
                    dvv[tid] = ov; dii[tid] = oi;
                }
            }
            __syncthreads();
        }
        if (tid == 0) bestk_sh[pix] = dii[0];
        __syncthreads();
    }

    if (tid < 64) out[gp0 + tid] = bestk_sh[tid];
}

extern "C" void kernel_launch(void* const* d_in, const int* in_sizes, int n_in,
                              void* d_out, int out_size, void* d_ws, size_t ws_size,
                              hipStream_t stream) {
    const float* x  = (const float*)d_in[0];   // (16, 512, 64, 64) f32
    const float* cc = (const float*)d_in[1];   // (1, 512, 512, 1, 1) f32 -> [k][c]
    int* out = (int*)d_out;                    // (16, 1, 64, 64) int32

    float* shalf = (float*)d_ws;               // 512 floats
    u16*   wcc   = (u16*)(shalf + NK);         // 1MB frag-ordered hi/lo bf16

    prep_pack<<<NK, 64, 0, stream>>>(cc, wcc, shalf);
    codebook_mfma<<<(16 * NHW) / 64, 256, 0, stream>>>(x, cc, wcc, shalf, out);
}